// Round 2
// baseline (183.657 us; speedup 1.0000x reference)
//
#include <hip/hip_runtime.h>
#include <hip/hip_bf16.h>

#define BATCH 64
#define IN_CH 128
#define ILEN  512
#define OLEN  505
#define OCH   128
#define KDIM  1024   // IN_CH * 8
#define BK    64     // K per chunk = 8 i-rows x 8 k
#define NCH   16     // KDIM / BK

using f32x4  = __attribute__((ext_vector_type(4))) float;
using bf16x8 = __attribute__((ext_vector_type(8))) short;

__device__ __forceinline__ short f2bf(float f) {
  union { __hip_bfloat16 h; short s; } u;
  u.h = __float2bfloat16(f);
  return u.s;
}

// Per block (l, oh): GEMM M=64(b) x N=64(o-half) x K=1024.
// B (weights) streamed DIRECT global->reg->cvt (no LDS, no barrier on the HBM stream).
// A (x window) staged via LDS bf16, XOR-swizzled, 1-chunk reg prefetch.
template <bool USE_TMP>
__global__ __launch_bounds__(256, 6) void lc1d_main(
    const float* __restrict__ x, const float* __restrict__ w,
    const float* __restrict__ bias, float* __restrict__ outp) {
  const int l   = blockIdx.x;
  const int oh  = blockIdx.y;        // o-half: 0 or 1
  const int tid = threadIdx.x;
  const int lane = tid & 63;
  const int wn  = tid >> 6;          // wave 0..3 -> o 16-slice
  const int r   = lane & 15;
  const int h   = lane >> 4;

  __shared__ short As[BATCH * BK];   // 8 KB, idx = b*BK + (col ^ ((b&7)<<3))

  f32x4 acc[4];
#pragma unroll
  for (int m = 0; m < 4; ++m) acc[m] = (f32x4){0.f, 0.f, 0.f, 0.f};

  const int o = oh * 64 + wn * 16 + r;
  const float* __restrict__ wrow = w + (size_t)l * (OCH * KDIM) + (size_t)o * KDIM;

  // A staging mapping: thread -> (il, kof) within chunk, tb = wave id
  const int kk  = tid & 63;
  const int il  = kk >> 3;           // 0..7 local i
  const int kof = kk & 7;
  const int tb  = tid >> 6;          // 0..3

  float aa[16];
  auto loadA = [&](int kc) {
    const float* xb = x + (size_t)(kc * 8 + il) * ILEN + l + kof;
#pragma unroll
    for (int it = 0; it < 16; ++it)
      aa[it] = xb[(size_t)(it * 4 + tb) * (IN_CH * ILEN)];
  };

  f32x4 bsta[2][2];
  auto loadB = [&](int kc) {
#pragma unroll
    for (int ks = 0; ks < 2; ++ks) {
      const float* p = wrow + kc * BK + ks * 32 + h * 8;  // 32B-aligned
      bsta[ks][0] = *reinterpret_cast<const f32x4*>(p);
      bsta[ks][1] = *reinterpret_cast<const f32x4*>(p + 4);
    }
  };

  loadA(0);
  for (int kc = 0; kc < NCH; ++kc) {
    loadB(kc);                        // HBM stream: in flight across barriers
    __syncthreads();                  // previous MFMA phase done reading As
#pragma unroll
    for (int it = 0; it < 16; ++it) { // store A chunk (waits only A vmcnt)
      const int b = it * 4 + tb;
      As[b * BK + (kk ^ ((b & 7) << 3))] = f2bf(aa[it]);
    }
    __syncthreads();
    if (kc + 1 < NCH) loadA(kc + 1);  // next A chunk (L3-resident) in flight
#pragma unroll
    for (int ks = 0; ks < 2; ++ks) {
      bf16x8 bfr;
#pragma unroll
      for (int j = 0; j < 4; ++j) {
        bfr[j]     = f2bf(bsta[ks][0][j]);
        bfr[4 + j] = f2bf(bsta[ks][1][j]);
      }
      const int koff = (ks * 32 + h * 8) ^ ((r & 7) << 3);
#pragma unroll
      for (int mt = 0; mt < 4; ++mt) {
        const bf16x8 afr =
            *reinterpret_cast<const bf16x8*>(&As[(mt * 16 + r) * BK + koff]);
        acc[mt] = __builtin_amdgcn_mfma_f32_16x16x32_bf16(afr, bfr, acc[mt], 0, 0, 0);
      }
    }
  }

  // C/D layout: col(o)=lane&15, row(b)=(lane>>4)*4+j
  if (USE_TMP) {
    float* t = outp + (size_t)l * (BATCH * OCH) + o;  // tmp[l][b][o]
#pragma unroll
    for (int mt = 0; mt < 4; ++mt)
#pragma unroll
      for (int j = 0; j < 4; ++j) {
        const int b = mt * 16 + h * 4 + j;
        t[(size_t)b * OCH] = acc[mt][j];
      }
  } else {
    const float bv = bias[o * OLEN + l];
#pragma unroll
    for (int mt = 0; mt < 4; ++mt)
#pragma unroll
      for (int j = 0; j < 4; ++j) {
        const int b = mt * 16 + h * 4 + j;
        outp[(size_t)b * (OCH * OLEN) + (size_t)o * OLEN + l] = acc[mt][j] + bv;
      }
  }
}

// tmp[l][b][o] -> out[b][o][l] (+bias), 64x64 LDS tile transpose
__global__ __launch_bounds__(256) void lc1d_tr(const float* __restrict__ tmp,
                                               const float* __restrict__ bias,
                                               float* __restrict__ out) {
  const int l0  = blockIdx.x * 64;
  const int bo0 = blockIdx.y * 64;
  const int tid = threadIdx.x;
  __shared__ float t[64][65];

  const int boj = tid & 63, lq = tid >> 6;
#pragma unroll
  for (int rr = 0; rr < 16; ++rr) {
    const int li = rr * 4 + lq;
    const int l  = l0 + li;
    if (l < OLEN) t[li][boj] = tmp[(size_t)l * (BATCH * OCH) + bo0 + boj];
  }
  __syncthreads();
  const int lj = tid & 63, bq = tid >> 6;
  const int l  = l0 + lj;
#pragma unroll
  for (int rr = 0; rr < 16; ++rr) {
    const int bl = rr * 4 + bq;
    const int bo = bo0 + bl;
    if (l < OLEN) {
      const int o = bo & (OCH - 1);
      out[(size_t)bo * OLEN + l] = t[lj][bl] + bias[o * OLEN + l];
    }
  }
}

extern "C" void kernel_launch(void* const* d_in, const int* in_sizes, int n_in,
                              void* d_out, int out_size, void* d_ws, size_t ws_size,
                              hipStream_t stream) {
  const float* x    = (const float*)d_in[0];
  const float* w    = (const float*)d_in[1];
  const float* bias = (const float*)d_in[2];
  float* out        = (float*)d_out;

  const size_t need = (size_t)OLEN * BATCH * OCH * sizeof(float);  // 16.5 MB
  if (ws_size >= need) {
    float* tmp = (float*)d_ws;
    lc1d_main<true><<<dim3(OLEN, 2), 256, 0, stream>>>(x, w, bias, tmp);
    lc1d_tr<<<dim3(8, 128), 256, 0, stream>>>(tmp, bias, out);
  } else {
    lc1d_main<false><<<dim3(OLEN, 2), 256, 0, stream>>>(x, w, bias, out);
  }
}